// Round 3
// baseline (938.122 us; speedup 1.0000x reference)
//
#include <hip/hip_runtime.h>
#include <math.h>

#define S_LEN 2048
#define NH 16
#define HDIM 64
#define BATCH 2
#define BHC 32          // BATCH*NH
#define KK 409          // int(2048 * (1.0 - 0.8)) per reference float math
#define DMODEL 1024

typedef __attribute__((ext_vector_type(8))) short bf16x8;   // 8 bf16 in 4 VGPRs
typedef __attribute__((ext_vector_type(4))) float f32x4;

// R11: LDS-resident score matrix. Row stride in u32 words: 16B-aligned
// (2052 % 4 == 0) and 2052 % 32 == 4 -> every wave access pattern below
// loads each of the 32 banks exactly 8x per b128 (baseline rate, no hot bank).
#define SSTR 2052       // 16 rows * 2052 * 4 B = 131,328 B  -> 1 block/CU
#define T_STR  40       // bf16 LDS tile row stride for gemm: 80 B, 16B-aligned

__device__ __forceinline__ unsigned f2ord(float f) {
    unsigned u = __float_as_uint(f);
    return (u & 0x80000000u) ? ~u : (u | 0x80000000u);
}
__device__ __forceinline__ float ord2f(unsigned v) {
    unsigned u = (v & 0x80000000u) ? (v & 0x7fffffffu) : ~v;
    return __uint_as_float(u);
}
__device__ __forceinline__ unsigned short f2bf(float f) {   // RNE
    unsigned u = __float_as_uint(f);
    u += 0x7fffu + ((u >> 16) & 1u);
    return (unsigned short)(u >> 16);
}
__device__ __forceinline__ float bf2f(unsigned short h) {
    return __uint_as_float(((unsigned)h) << 16);
}

// ---------------------------------------------------------------------------
// fp32 -> bf16 hi/lo split (vectorized float4 / ushort4), n4 = elements/4
// ---------------------------------------------------------------------------
__global__ __launch_bounds__(256)
void split32(const float* __restrict__ in, unsigned short* __restrict__ hi,
             unsigned short* __restrict__ lo, int n4)
{
    const int i = blockIdx.x * 256 + threadIdx.x;
    if (i < n4) {
        const float4 v = ((const float4*)in)[i];
        ushort4 h, l;
        h.x = f2bf(v.x); l.x = f2bf(v.x - bf2f(h.x));
        h.y = f2bf(v.y); l.y = f2bf(v.y - bf2f(h.y));
        h.z = f2bf(v.z); l.z = f2bf(v.z - bf2f(h.z));
        h.w = f2bf(v.w); l.w = f2bf(v.w - bf2f(h.w));
        ((ushort4*)hi)[i] = h;
        ((ushort4*)lo)[i] = l;
    }
}

// ---------------------------------------------------------------------------
// LDS-staged split-bf16 3-pass MFMA GEMM (unchanged — R8 banked structure).
//   C[m][n] = sum_k A[m][k]*B[n][k] + bias[n]
// ---------------------------------------------------------------------------
__global__ __launch_bounds__(256)
void gemm_mfma(const unsigned short* __restrict__ Ah, const unsigned short* __restrict__ Al,
               const unsigned short* __restrict__ Bh, const unsigned short* __restrict__ Bl,
               const float* __restrict__ bias, void* __restrict__ out0,
               void* __restrict__ out1, int mode)
{
    __shared__ __align__(16) unsigned short sAh[128 * T_STR];
    __shared__ __align__(16) unsigned short sAl[128 * T_STR];
    __shared__ __align__(16) unsigned short sBh[64 * T_STR];
    __shared__ __align__(16) unsigned short sBl[64 * T_STR];

    const int tid  = threadIdx.x;
    const int lane = tid & 63;
    const int w    = tid >> 6;
    const int q15  = lane & 15;
    const int quad = lane >> 4;
    const int n0b = blockIdx.x * 64;
    const int m0b = blockIdx.y * 128;
    const int wm = (w >> 1) * 64;
    const int wn = (w & 1) * 32;

    const int ar0 = tid >> 2, aks0 = (tid & 3) * 8;
    const int ar1 = (tid + 256) >> 2, aks1 = aks0;
    const int br = tid >> 2, bks = (tid & 3) * 8;

    const unsigned short* gAh0 = Ah + (size_t)(m0b + ar0) * 1024 + aks0;
    const unsigned short* gAh1 = Ah + (size_t)(m0b + ar1) * 1024 + aks1;
    const unsigned short* gAl0 = Al + (size_t)(m0b + ar0) * 1024 + aks0;
    const unsigned short* gAl1 = Al + (size_t)(m0b + ar1) * 1024 + aks1;
    const unsigned short* gBh = Bh + (size_t)(n0b + br) * 1024 + bks;
    const unsigned short* gBl = Bl + (size_t)(n0b + br) * 1024 + bks;

    f32x4 acc[4][2];
#pragma unroll
    for (int mt = 0; mt < 4; ++mt)
#pragma unroll
        for (int nt = 0; nt < 2; ++nt) acc[mt][nt] = (f32x4){0.f, 0.f, 0.f, 0.f};

#pragma unroll 1
    for (int k0 = 0; k0 < 1024; k0 += 32) {
        const bf16x8 vah0 = *(const bf16x8*)(gAh0 + k0);
        const bf16x8 vah1 = *(const bf16x8*)(gAh1 + k0);
        const bf16x8 val0 = *(const bf16x8*)(gAl0 + k0);
        const bf16x8 val1 = *(const bf16x8*)(gAl1 + k0);
        const bf16x8 vbh  = *(const bf16x8*)(gBh + k0);
        const bf16x8 vbl  = *(const bf16x8*)(gBl + k0);
        __syncthreads();
        *(bf16x8*)(sAh + ar0 * T_STR + aks0) = vah0;
        *(bf16x8*)(sAh + ar1 * T_STR + aks1) = vah1;
        *(bf16x8*)(sAl + ar0 * T_STR + aks0) = val0;
        *(bf16x8*)(sAl + ar1 * T_STR + aks1) = val1;
        *(bf16x8*)(sBh + br * T_STR + bks) = vbh;
        *(bf16x8*)(sBl + br * T_STR + bks) = vbl;
        __syncthreads();

        bf16x8 fbh[2], fbl[2];
#pragma unroll
        for (int nt = 0; nt < 2; ++nt) {
            fbh[nt] = *(const bf16x8*)(sBh + (wn + nt * 16 + q15) * T_STR + quad * 8);
            fbl[nt] = *(const bf16x8*)(sBl + (wn + nt * 16 + q15) * T_STR + quad * 8);
        }
#pragma unroll
        for (int mt = 0; mt < 4; ++mt) {
            const bf16x8 fah = *(const bf16x8*)(sAh + (wm + mt * 16 + q15) * T_STR + quad * 8);
            const bf16x8 fal = *(const bf16x8*)(sAl + (wm + mt * 16 + q15) * T_STR + quad * 8);
#pragma unroll
            for (int nt = 0; nt < 2; ++nt) {
                acc[mt][nt] = __builtin_amdgcn_mfma_f32_16x16x32_bf16(fah, fbh[nt], acc[mt][nt], 0, 0, 0);
                acc[mt][nt] = __builtin_amdgcn_mfma_f32_16x16x32_bf16(fah, fbl[nt], acc[mt][nt], 0, 0, 0);
                acc[mt][nt] = __builtin_amdgcn_mfma_f32_16x16x32_bf16(fal, fbh[nt], acc[mt][nt], 0, 0, 0);
            }
        }
    }

#pragma unroll
    for (int nt = 0; nt < 2; ++nt) {
        const int n = n0b + wn + nt * 16 + q15;
        const float bv = bias[n];
#pragma unroll
        for (int mt = 0; mt < 4; ++mt) {
            const int mb = m0b + wm + mt * 16 + quad * 4;
#pragma unroll
            for (int rg = 0; rg < 4; ++rg) {
                const int m = mb + rg;
                const float o = acc[mt][nt][rg] + bv;
                if (mode == 0) {
                    ((float*)out0)[(size_t)m * 1024 + n] = o;
                } else {
                    const int b = m >> 11, s = m & 2047;
                    const int h = n >> 6, hd = n & 63;
                    const size_t base = ((size_t)((b * NH + h) * S_LEN + s)) * HDIM + hd;
                    if (mode == 3) {
                        ((unsigned short*)out0)[base] = f2bf(o);
                    } else {
                        const unsigned short oh = f2bf(o);
                        ((unsigned short*)out0)[base] = oh;
                        ((unsigned short*)out1)[base] = f2bf(o - bf2f(oh));
                    }
                }
            }
        }
    }
}

// ---------------------------------------------------------------------------
// V bf16 [bh][s][64] -> Vt bf16 [bh][64][2048]  (B-operand layout for PV MFMA)
// ---------------------------------------------------------------------------
__global__ __launch_bounds__(256)
void transpose_v16(const unsigned short* __restrict__ V, unsigned short* __restrict__ Vt)
{
    __shared__ unsigned short t[64][72];
    const int tid = threadIdx.x;
    const int s0 = blockIdx.x * 64;
    const int bh = blockIdx.y;
    const unsigned short* Vb = V + (size_t)bh * S_LEN * HDIM;
#pragma unroll
    for (int i = 0; i < 4; ++i) {
        const int f = tid + i * 256;
        const int s = f >> 4;
        const int hq = (f & 15) * 4;
        const ushort4 v = *(const ushort4*)(Vb + (size_t)(s0 + s) * HDIM + hq);
        t[s][hq + 0] = v.x; t[s][hq + 1] = v.y; t[s][hq + 2] = v.z; t[s][hq + 3] = v.w;
    }
    __syncthreads();
    unsigned short* Vtb = Vt + (size_t)bh * HDIM * S_LEN;
#pragma unroll
    for (int i = 0; i < 4; ++i) {
        const int f = tid + i * 256;
        const int hd = f >> 4;
        const int sq = (f & 15) * 4;
        ushort4 v;
        v.x = t[sq + 0][hd]; v.y = t[sq + 1][hd];
        v.z = t[sq + 2][hd]; v.w = t[sq + 3][hd];
        *(ushort4*)(Vtb + (size_t)hd * S_LEN + s0 + sq) = v;
    }
}

// ---------------------------------------------------------------------------
// pack hi-16 of 8 consecutive score words (= in-place bf16 P) into a bf16x8
// ---------------------------------------------------------------------------
__device__ __forceinline__ bf16x8 pack_hi8(const uint4 a0, const uint4 a1)
{
    union { unsigned u[4]; bf16x8 v; } c;
    c.u[0] = (a0.x >> 16) | (a0.y & 0xffff0000u);
    c.u[1] = (a0.z >> 16) | (a0.w & 0xffff0000u);
    c.u[2] = (a1.x >> 16) | (a1.y & 0xffff0000u);
    c.u[3] = (a1.z >> 16) | (a1.w & 0xffff0000u);
    return c.v;
}

// ---------------------------------------------------------------------------
// Fused attention R11 — LDS-resident scores, zero scratch.
//
// Diagnosis driving this rewrite (R10 counters): VGPR=44 (u0/u1 spilled to
// scratch), WRITE_SIZE 557 MB ~= scratch write-through (AO is 16 MB),
// FETCH 689 MB >> 56 MB unique inputs, all pipes idle (Mfma 4.4 / VALU 26 /
// HBM 25%).  The 32-bit rank-count search re-read 128 KB/block of L2-thrashed
// scratch ~33x -> HBM-latency-bound.
//
// New structure:
//  * QK^T writes ord-uint scores directly to final LDS home [16][SSTR]
//    (131 KB, 1 block/CU) — exchange buffer and u arrays gone.
//  * Select: each wave loads its row slice ONCE into a statically-indexed
//    8x uint4 register block (scoped — not R6's persistent arrays), then
//    rank-count binary search on registers.  Exact wave count via 6
//    ballot bit-planes (cnt lands in SGPRs -> uniform branch).
//  * Softmax P-pass reuses the same registers and writes bf16 P IN PLACE
//    into the hi 16 bits of each score word (same lane reads+writes its own
//    words -> race-free).  PV unpacks with 2x ds_read_b128 + 4 OR/shift.
// ---------------------------------------------------------------------------
__global__ __launch_bounds__(512, 2)
void attn_kernel(const unsigned short* __restrict__ Qh, const unsigned short* __restrict__ Ql,
                 const unsigned short* __restrict__ Kh, const unsigned short* __restrict__ Kl,
                 const unsigned short* __restrict__ Vt,
                 unsigned short* __restrict__ AOh, unsigned short* __restrict__ AOl)
{
    extern __shared__ __align__(16) char smem[];
    unsigned* S = (unsigned*)smem;          // [16][SSTR] ord scores / bf16-P overlay
    float* Opart = (float*)smem;            // overlay [8][16][64] after PV reads done

    const int tid  = threadIdx.x;
    const int lane = tid & 63;
    const int w    = tid >> 6;
    const int q15  = lane & 15;
    const int quad = lane >> 4;

    // XCD swizzle: 4 heads per XCD -> K+V working set ~3 MB, fits 4 MB L2
    const int blk = blockIdx.x;
    const int bh  = (blk & 7) * 4 + ((blk >> 3) & 3);
    const int q0  = (blk >> 5) * 16;

    // ---- Q B-frags direct from global ----
    const size_t qrow = ((size_t)bh * S_LEN + q0 + q15) * HDIM;
    const bf16x8 bqh0 = *(const bf16x8*)(Qh + qrow + quad * 8);
    const bf16x8 bqh1 = *(const bf16x8*)(Qh + qrow + 32 + quad * 8);
    const bf16x8 bql0 = *(const bf16x8*)(Ql + qrow + quad * 8);
    const bf16x8 bql1 = *(const bf16x8*)(Ql + qrow + 32 + quad * 8);

    const size_t kbase = (size_t)bh * S_LEN * HDIM;

    // ---- phase 1: QK^T, all 16 key-tiles per wave, straight to LDS ----
#pragma unroll 4
    for (int t = 0; t < 16; ++t) {
        const int key = w * 256 + t * 16 + q15;     // A-frag m
        const unsigned short* kh = Kh + kbase + (size_t)key * HDIM + quad * 8;
        const unsigned short* kl = Kl + kbase + (size_t)key * HDIM + quad * 8;
        const bf16x8 akh0 = *(const bf16x8*)(kh);
        const bf16x8 akh1 = *(const bf16x8*)(kh + 32);
        const bf16x8 akl0 = *(const bf16x8*)(kl);
        const bf16x8 akl1 = *(const bf16x8*)(kl + 32);
        f32x4 c = {0.f, 0.f, 0.f, 0.f};
        c = __builtin_amdgcn_mfma_f32_16x16x32_bf16(akh0, bqh0, c, 0, 0, 0);
        c = __builtin_amdgcn_mfma_f32_16x16x32_bf16(akh1, bqh1, c, 0, 0, 0);
        c = __builtin_amdgcn_mfma_f32_16x16x32_bf16(akh0, bql0, c, 0, 0, 0);
        c = __builtin_amdgcn_mfma_f32_16x16x32_bf16(akh1, bql1, c, 0, 0, 0);
        c = __builtin_amdgcn_mfma_f32_16x16x32_bf16(akl0, bqh0, c, 0, 0, 0);
        c = __builtin_amdgcn_mfma_f32_16x16x32_bf16(akl1, bqh1, c, 0, 0, 0);
        c = c * 0.125f;
        // C-layout: col=lane&15=q(row of S), row-in-tile=quad*4+reg=key(col)
        uint4 o;
        o.x = f2ord(c[0]); o.y = f2ord(c[1]); o.z = f2ord(c[2]); o.w = f2ord(c[3]);
        *(uint4*)(S + q15 * SSTR + w * 256 + t * 16 + quad * 4) = o;
    }
    __syncthreads();   // full [16][2048] score matrix visible

    // ---- phase 2: per-row select + softmax, in-place bf16 P ----
    float invd[2];
    const int r0 = 2 * w;
#pragma unroll
    for (int rr = 0; rr < 2; ++rr) {
        const int r = r0 + rr;
        unsigned* R = S + r * SSTR;

        // load this lane's 32-element slice once (static indices -> VGPRs)
        uint4 va[8];
#pragma unroll
        for (int i = 0; i < 8; ++i) va[i] = *(const uint4*)(R + i * 256 + lane * 4);

        // row max
        unsigned umx = 0u;
#pragma unroll
        for (int i = 0; i < 8; ++i) {
            umx = va[i].x > umx ? va[i].x : umx;
            umx = va[i].y > umx ? va[i].y : umx;
            umx = va[i].z > umx ? va[i].z : umx;
            umx = va[i].w > umx ? va[i].w : umx;
        }
#pragma unroll
        for (int off = 32; off >= 1; off >>= 1) {
            const unsigned o = (unsigned)__shfl_xor((int)umx, off);
            umx = o > umx ? o : umx;
        }
        const float mx = ord2f(umx);

        // rank-count binary search, all-register; exact wave sum via
        // 6 ballot bit-planes (c in 0..32)
        unsigned T = 0u;
#pragma unroll 1
        for (int b = 31; b >= 0; --b) {
            const unsigned X = T | (1u << b);
            int c = 0;
#pragma unroll
            for (int i = 0; i < 8; ++i) {
                c += (va[i].x >= X) + (va[i].y >= X) + (va[i].z >= X) + (va[i].w >= X);
            }
            int cnt = 0;
#pragma unroll
            for (int bb = 0; bb < 6; ++bb)
                cnt += (int)(__builtin_popcountll(__ballot((c >> bb) & 1)) << bb);
            if (cnt >= KK) {
                T = X;
                if (cnt == KK) {   // answer = min over {u >= X}
                    unsigned mn = 0xffffffffu;
#pragma unroll
                    for (int i = 0; i < 8; ++i) {
                        unsigned v;
                        v = va[i].x >= X ? va[i].x : 0xffffffffu; mn = v < mn ? v : mn;
                        v = va[i].y >= X ? va[i].y : 0xffffffffu; mn = v < mn ? v : mn;
                        v = va[i].z >= X ? va[i].z : 0xffffffffu; mn = v < mn ? v : mn;
                        v = va[i].w >= X ? va[i].w : 0xffffffffu; mn = v < mn ? v : mn;
                    }
#pragma unroll
                    for (int off = 32; off >= 1; off >>= 1) {
                        const unsigned o = (unsigned)__shfl_xor((int)mn, off);
                        mn = o < mn ? o : mn;
                    }
                    T = mn;
                    break;
                }
            }
        }

        // softmax numerators from registers; bf16 P into hi-half, in place
        float lsum = 0.f;
#pragma unroll
        for (int i = 0; i < 8; ++i) {
            const uint4 v = va[i];
            const float e0 = (v.x >= T) ? __expf(ord2f(v.x) - mx) : 0.f;
            const float e1 = (v.y >= T) ? __expf(ord2f(v.y) - mx) : 0.f;
            const float e2 = (v.z >= T) ? __expf(ord2f(v.z) - mx) : 0.f;
            const float e3 = (v.w >= T) ? __expf(ord2f(v.w) - mx) : 0.f;
            uint4 pw;
            pw.x = ((unsigned)f2bf(e0)) << 16;
            pw.y = ((unsigned)f2bf(e1)) << 16;
            pw.z = ((unsigned)f2bf(e2)) << 16;
            pw.w = ((unsigned)f2bf(e3)) << 16;
            *(uint4*)(R + i * 256 + lane * 4) = pw;
            lsum += e0 + e1 + e2 + e3;
        }
#pragma unroll
        for (int off = 32; off >= 1; off >>= 1) lsum += __shfl_xor(lsum, off);
        invd[rr] = 1.f / lsum;
    }
    __syncthreads();   // all P visible

    // ---- phase 3: dense PV via bf16 MFMA, wave w keys [256w,256w+256) ----
    {
        f32x4 oacc[4];
#pragma unroll
        for (int ht = 0; ht < 4; ++ht) oacc[ht] = (f32x4){0.f, 0.f, 0.f, 0.f};
        const size_t vtb = (size_t)bh * HDIM * S_LEN;
        const unsigned* Srow = S + q15 * SSTR;
#pragma unroll 2
        for (int ks = 0; ks < 8; ++ks) {
            const int key0 = w * 256 + ks * 32 + quad * 8;
            const uint4 a0 = *(const uint4*)(Srow + key0);
            const uint4 a1 = *(const uint4*)(Srow + key0 + 4);
            const bf16x8 ap = pack_hi8(a0, a1);                      // A[m=q][k=key]
#pragma unroll
            for (int ht = 0; ht < 4; ++ht) {
                const int hd = ht * 16 + q15;                        // B[k=key][n=hd]
                const bf16x8 bv = *(const bf16x8*)(Vt + vtb + (size_t)hd * S_LEN + key0);
                oacc[ht] = __builtin_amdgcn_mfma_f32_16x16x32_bf16(ap, bv, oacc[ht], 0, 0, 0);
            }
        }
        __syncthreads();   // all P reads done; score region dead -> Opart live
        // D[m=q][n=hd]: col=lane&15=hd-in-tile, row=quad*4+reg=q
#pragma unroll
        for (int ht = 0; ht < 4; ++ht)
#pragma unroll
            for (int rg = 0; rg < 4; ++rg)
                Opart[w * 1024 + (quad * 4 + rg) * 64 + ht * 16 + q15] = oacc[ht][rg];
    }
    __syncthreads();

    // ---- final: reduce 8 partials, scale, write AO as bf16 hi/lo ----
    {
        const int r1 = r0 + 1;
        float s0 = 0.f, s1 = 0.f;
#pragma unroll
        for (int ww = 0; ww < 8; ++ww) {
            s0 += Opart[ww * 1024 + r0 * 64 + lane];
            s1 += Opart[ww * 1024 + r1 * 64 + lane];
        }
        const int b = bh >> 4, h = bh & 15;
        const float o0 = s0 * invd[0];
        const float o1 = s1 * invd[1];
        const size_t i0 = ((size_t)(b * S_LEN + q0 + r0)) * DMODEL + h * HDIM + lane;
        const size_t i1 = ((size_t)(b * S_LEN + q0 + r1)) * DMODEL + h * HDIM + lane;
        const unsigned short h0 = f2bf(o0), h1 = f2bf(o1);
        AOh[i0] = h0; AOl[i0] = f2bf(o0 - bf2f(h0));
        AOh[i1] = h1; AOl[i1] = f2bf(o1 - bf2f(h1));
    }
}

// ---------------------------------------------------------------------------
extern "C" void kernel_launch(void* const* d_in, const int* in_sizes, int n_in,
                              void* d_out, int out_size, void* d_ws, size_t ws_size,
                              hipStream_t stream)
{
    const float* X  = (const float*)d_in[0];
    const float* Wq = (const float*)d_in[1];
    const float* bq = (const float*)d_in[2];
    const float* Wk = (const float*)d_in[3];
    const float* bk = (const float*)d_in[4];
    const float* Wv = (const float*)d_in[5];
    const float* bv = (const float*)d_in[6];
    const float* Wo = (const float*)d_in[7];
    const float* bo = (const float*)d_in[8];

    char* p = (char*)d_ws;
    const size_t NEL = (size_t)BHC * S_LEN * HDIM;   // 4,194,304
    unsigned short* Q16h = (unsigned short*)p; p += NEL * 2;
    unsigned short* Q16l = (unsigned short*)p; p += NEL * 2;
    unsigned short* K16h = (unsigned short*)p; p += NEL * 2;
    unsigned short* K16l = (unsigned short*)p; p += NEL * 2;
    unsigned short* Vb16 = (unsigned short*)p; p += NEL * 2;
    unsigned short* Vt16 = (unsigned short*)p; p += NEL * 2;
    unsigned short* Xh   = (unsigned short*)p; p += NEL * 2;
    unsigned short* Xl   = (unsigned short*)p; p += NEL * 2;
    unsigned short* AOh  = (unsigned short*)p; p += NEL * 2;
    unsigned short* AOl  = (unsigned short*)p; p += NEL * 2;
    unsigned short* Wqh  = (unsigned short*)p; p += DMODEL * DMODEL * 2;
    unsigned short* Wql  = (unsigned short*)p; p += DMODEL * DMODEL * 2;
    unsigned short* Wkh  = (unsigned short*)p; p += DMODEL * DMODEL * 2;
    unsigned short* Wkl  = (unsigned short*)p; p += DMODEL * DMODEL * 2;
    unsigned short* Wvh  = (unsigned short*)p; p += DMODEL * DMODEL * 2;
    unsigned short* Wvl  = (unsigned short*)p; p += DMODEL * DMODEL * 2;
    unsigned short* Woh  = (unsigned short*)p; p += DMODEL * DMODEL * 2;
    unsigned short* Wol  = (unsigned short*)p; p += DMODEL * DMODEL * 2;

    const int attn_lds = 16 * SSTR * 4;   // 131,328 B -> 1 block/CU
    hipFuncSetAttribute((const void*)attn_kernel,
                        hipFuncAttributeMaxDynamicSharedMemorySize, attn_lds);

    const int X4 = (int)(NEL / 4);                 // 1,048,576
    const int W4 = DMODEL * DMODEL / 4;            //   262,144

    // ---- input splits ----
    split32<<<(X4 + 255) / 256, 256, 0, stream>>>(X,  Xh,  Xl,  X4);
    split32<<<(W4 + 255) / 256, 256, 0, stream>>>(Wq, Wqh, Wql, W4);
    split32<<<(W4 + 255) / 256, 256, 0, stream>>>(Wk, Wkh, Wkl, W4);
    split32<<<(W4 + 255) / 256, 256, 0, stream>>>(Wv, Wvh, Wvl, W4);
    split32<<<(W4 + 255) / 256, 256, 0, stream>>>(Wo, Woh, Wol, W4);

    // ---- projections (LDS-staged MFMA split-bf16): tiles 128m x 64n ----
    const dim3 ggrid(16, 32, 1);
    gemm_mfma<<<ggrid, 256, 0, stream>>>(Xh, Xl, Wqh, Wql, bq, Q16h, Q16l, 2);
    gemm_mfma<<<ggrid, 256, 0, stream>>>(Xh, Xl, Wkh, Wkl, bk, K16h, K16l, 2);
    gemm_mfma<<<ggrid, 256, 0, stream>>>(Xh, Xl, Wvh, Wvl, bv, Vb16, nullptr, 3);
    transpose_v16<<<dim3(32, 32, 1), 256, 0, stream>>>(Vb16, Vt16);

    // ---- fused attention (R11: LDS-resident scores, zero scratch) ----
    attn_kernel<<<4096, 512, attn_lds, stream>>>(Q16h, Q16l, K16h, K16l, Vt16, AOh, AOl);

    // ---- output projection ----
    gemm_mfma<<<ggrid, 256, 0, stream>>>(AOh, AOl, Woh, Wol, bo, d_out, nullptr, 0);
}

// Round 5
// 815.101 us; speedup vs baseline: 1.1509x; 1.1509x over previous
//
#include <hip/hip_runtime.h>
#include <math.h>

#define S_LEN 2048
#define NH 16
#define HDIM 64
#define BATCH 2
#define BHC 32          // BATCH*NH
#define KK 409          // int(2048 * (1.0 - 0.8)) per reference float math
#define DMODEL 1024

typedef __attribute__((ext_vector_type(8))) short bf16x8;   // 8 bf16 in 4 VGPRs
typedef __attribute__((ext_vector_type(4))) float f32x4;

// LDS-resident score matrix. Row stride in u32 words: 16B-aligned
// (2052 % 4 == 0) and 2052 % 32 == 4 -> no hot bank on any access below.
#define SSTR 2052       // 16 rows * 2052 * 4 B = 131,328 B  -> 1 block/CU
#define T_STR  40       // bf16 LDS tile row stride for gemm: 80 B, 16B-aligned

__device__ __forceinline__ unsigned f2ord(float f) {
    unsigned u = __float_as_uint(f);
    return (u & 0x80000000u) ? ~u : (u | 0x80000000u);
}
__device__ __forceinline__ float ord2f(unsigned v) {
    unsigned u = (v & 0x80000000u) ? (v & 0x7fffffffu) : ~v;
    return __uint_as_float(u);
}
__device__ __forceinline__ unsigned short f2bf(float f) {   // RNE
    unsigned u = __float_as_uint(f);
    u += 0x7fffu + ((u >> 16) & 1u);
    return (unsigned short)(u >> 16);
}
__device__ __forceinline__ float bf2f(unsigned short h) {
    return __uint_as_float(((unsigned)h) << 16);
}

// ---------------------------------------------------------------------------
// fp32 -> bf16 hi/lo split (vectorized float4 / ushort4), n4 = elements/4
// ---------------------------------------------------------------------------
__global__ __launch_bounds__(256)
void split32(const float* __restrict__ in, unsigned short* __restrict__ hi,
             unsigned short* __restrict__ lo, int n4)
{
    const int i = blockIdx.x * 256 + threadIdx.x;
    if (i < n4) {
        const float4 v = ((const float4*)in)[i];
        ushort4 h, l;
        h.x = f2bf(v.x); l.x = f2bf(v.x - bf2f(h.x));
        h.y = f2bf(v.y); l.y = f2bf(v.y - bf2f(h.y));
        h.z = f2bf(v.z); l.z = f2bf(v.z - bf2f(h.z));
        h.w = f2bf(v.w); l.w = f2bf(v.w - bf2f(h.w));
        ((ushort4*)hi)[i] = h;
        ((ushort4*)lo)[i] = l;
    }
}

// ---------------------------------------------------------------------------
// LDS-staged split-bf16 3-pass MFMA GEMM (unchanged — R8 banked structure).
//   C[m][n] = sum_k A[m][k]*B[n][k] + bias[n]
// ---------------------------------------------------------------------------
__global__ __launch_bounds__(256)
void gemm_mfma(const unsigned short* __restrict__ Ah, const unsigned short* __restrict__ Al,
               const unsigned short* __restrict__ Bh, const unsigned short* __restrict__ Bl,
               const float* __restrict__ bias, void* __restrict__ out0,
               void* __restrict__ out1, int mode)
{
    __shared__ __align__(16) unsigned short sAh[128 * T_STR];
    __shared__ __align__(16) unsigned short sAl[128 * T_STR];
    __shared__ __align__(16) unsigned short sBh[64 * T_STR];
    __shared__ __align__(16) unsigned short sBl[64 * T_STR];

    const int tid  = threadIdx.x;
    const int lane = tid & 63;
    const int w    = tid >> 6;
    const int q15  = lane & 15;
    const int quad = lane >> 4;
    const int n0b = blockIdx.x * 64;
    const int m0b = blockIdx.y * 128;
    const int wm = (w >> 1) * 64;
    const int wn = (w & 1) * 32;

    const int ar0 = tid >> 2, aks0 = (tid & 3) * 8;
    const int ar1 = (tid + 256) >> 2, aks1 = aks0;
    const int br = tid >> 2, bks = (tid & 3) * 8;

    const unsigned short* gAh0 = Ah + (size_t)(m0b + ar0) * 1024 + aks0;
    const unsigned short* gAh1 = Ah + (size_t)(m0b + ar1) * 1024 + aks1;
    const unsigned short* gAl0 = Al + (size_t)(m0b + ar0) * 1024 + aks0;
    const unsigned short* gAl1 = Al + (size_t)(m0b + ar1) * 1024 + aks1;
    const unsigned short* gBh = Bh + (size_t)(n0b + br) * 1024 + bks;
    const unsigned short* gBl = Bl + (size_t)(n0b + br) * 1024 + bks;

    f32x4 acc[4][2];
#pragma unroll
    for (int mt = 0; mt < 4; ++mt)
#pragma unroll
        for (int nt = 0; nt < 2; ++nt) acc[mt][nt] = (f32x4){0.f, 0.f, 0.f, 0.f};

#pragma unroll 1
    for (int k0 = 0; k0 < 1024; k0 += 32) {
        const bf16x8 vah0 = *(const bf16x8*)(gAh0 + k0);
        const bf16x8 vah1 = *(const bf16x8*)(gAh1 + k0);
        const bf16x8 val0 = *(const bf16x8*)(gAl0 + k0);
        const bf16x8 val1 = *(const bf16x8*)(gAl1 + k0);
        const bf16x8 vbh  = *(const bf16x8*)(gBh + k0);
        const bf16x8 vbl  = *(const bf16x8*)(gBl + k0);
        __syncthreads();
        *(bf16x8*)(sAh + ar0 * T_STR + aks0) = vah0;
        *(bf16x8*)(sAh + ar1 * T_STR + aks1) = vah1;
        *(bf16x8*)(sAl + ar0 * T_STR + aks0) = val0;
        *(bf16x8*)(sAl + ar1 * T_STR + aks1) = val1;
        *(bf16x8*)(sBh + br * T_STR + bks) = vbh;
        *(bf16x8*)(sBl + br * T_STR + bks) = vbl;
        __syncthreads();

        bf16x8 fbh[2], fbl[2];
#pragma unroll
        for (int nt = 0; nt < 2; ++nt) {
            fbh[nt] = *(const bf16x8*)(sBh + (wn + nt * 16 + q15) * T_STR + quad * 8);
            fbl[nt] = *(const bf16x8*)(sBl + (wn + nt * 16 + q15) * T_STR + quad * 8);
        }
#pragma unroll
        for (int mt = 0; mt < 4; ++mt) {
            const bf16x8 fah = *(const bf16x8*)(sAh + (wm + mt * 16 + q15) * T_STR + quad * 8);
            const bf16x8 fal = *(const bf16x8*)(sAl + (wm + mt * 16 + q15) * T_STR + quad * 8);
#pragma unroll
            for (int nt = 0; nt < 2; ++nt) {
                acc[mt][nt] = __builtin_amdgcn_mfma_f32_16x16x32_bf16(fah, fbh[nt], acc[mt][nt], 0, 0, 0);
                acc[mt][nt] = __builtin_amdgcn_mfma_f32_16x16x32_bf16(fah, fbl[nt], acc[mt][nt], 0, 0, 0);
                acc[mt][nt] = __builtin_amdgcn_mfma_f32_16x16x32_bf16(fal, fbh[nt], acc[mt][nt], 0, 0, 0);
            }
        }
    }

#pragma unroll
    for (int nt = 0; nt < 2; ++nt) {
        const int n = n0b + wn + nt * 16 + q15;
        const float bv = bias[n];
#pragma unroll
        for (int mt = 0; mt < 4; ++mt) {
            const int mb = m0b + wm + mt * 16 + quad * 4;
#pragma unroll
            for (int rg = 0; rg < 4; ++rg) {
                const int m = mb + rg;
                const float o = acc[mt][nt][rg] + bv;
                if (mode == 0) {
                    ((float*)out0)[(size_t)m * 1024 + n] = o;
                } else {
                    const int b = m >> 11, s = m & 2047;
                    const int h = n >> 6, hd = n & 63;
                    const size_t base = ((size_t)((b * NH + h) * S_LEN + s)) * HDIM + hd;
                    if (mode == 3) {
                        ((unsigned short*)out0)[base] = f2bf(o);
                    } else {
                        const unsigned short oh = f2bf(o);
                        ((unsigned short*)out0)[base] = oh;
                        ((unsigned short*)out1)[base] = f2bf(o - bf2f(oh));
                    }
                }
            }
        }
    }
}

// ---------------------------------------------------------------------------
// V bf16 [bh][s][64] -> Vt bf16 [bh][64][2048]  (B-operand layout for PV MFMA)
// ---------------------------------------------------------------------------
__global__ __launch_bounds__(256)
void transpose_v16(const unsigned short* __restrict__ V, unsigned short* __restrict__ Vt)
{
    __shared__ unsigned short t[64][72];
    const int tid = threadIdx.x;
    const int s0 = blockIdx.x * 64;
    const int bh = blockIdx.y;
    const unsigned short* Vb = V + (size_t)bh * S_LEN * HDIM;
#pragma unroll
    for (int i = 0; i < 4; ++i) {
        const int f = tid + i * 256;
        const int s = f >> 4;
        const int hq = (f & 15) * 4;
        const ushort4 v = *(const ushort4*)(Vb + (size_t)(s0 + s) * HDIM + hq);
        t[s][hq + 0] = v.x; t[s][hq + 1] = v.y; t[s][hq + 2] = v.z; t[s][hq + 3] = v.w;
    }
    __syncthreads();
    unsigned short* Vtb = Vt + (size_t)bh * HDIM * S_LEN;
#pragma unroll
    for (int i = 0; i < 4; ++i) {
        const int f = tid + i * 256;
        const int hd = f >> 4;
        const int sq = (f & 15) * 4;
        ushort4 v;
        v.x = t[sq + 0][hd]; v.y = t[sq + 1][hd];
        v.z = t[sq + 2][hd]; v.w = t[sq + 3][hd];
        *(ushort4*)(Vtb + (size_t)hd * S_LEN + s0 + sq) = v;
    }
}

// ---------------------------------------------------------------------------
// pack hi-16 of 8 consecutive score words (= in-place bf16 P) into a bf16x8
// ---------------------------------------------------------------------------
__device__ __forceinline__ bf16x8 pack_hi8(const uint4 a0, const uint4 a1)
{
    union { unsigned u[4]; bf16x8 v; } c;
    c.u[0] = (a0.x >> 16) | (a0.y & 0xffff0000u);
    c.u[1] = (a0.z >> 16) | (a0.w & 0xffff0000u);
    c.u[2] = (a1.x >> 16) | (a1.y & 0xffff0000u);
    c.u[3] = (a1.z >> 16) | (a1.w & 0xffff0000u);
    return c.v;
}

// ---------------------------------------------------------------------------
// R12 phase-2 row pass — ALL NAMED SCALARS, no local arrays anywhere.
// (R11 post-mortem: VGPR_Count=44 proved uint4 va[8] was demoted to scratch;
//  the bit-serial select then re-read L2-resident scratch ~256x at ~200cyc
//  = 45us/block = the whole runtime.  Rule #20: any runtime-indexed local
//  array goes to scratch; named scalars cannot.)
//
// Select = rank-count binary search on BIT-PLANES:
//   one 32x32 in-register bit transpose (t{b} bit j = bit b of u{j}), then
//   per bit: eb = E & t_b; cnt = gcnt + wave_sum(popc(eb)) via 6 ballots;
//   cnt>=KK -> set bit (E=eb); else gcnt=cnt, E&=~t_b.  Early exit cnt==KK.
//   Threshold = min{u >= T} (== T when loop completes).  Identical semantics
//   to the proven R8/R10/R11 rank-count select.
// ---------------------------------------------------------------------------
#define TRP(AK, AKJ, J, M) { const unsigned _t = (((AK) >> (J)) ^ (AKJ)) & (M); \
                             (AK) ^= _t << (J); (AKJ) ^= _t; }
#define UMX(A, B) ((A) > (B) ? (A) : (B))

#define SELSTEP(TB, BITV) { \
    const unsigned eb = E & (TB); \
    const int cl = __builtin_popcount(eb); \
    int cnt = gcnt; \
    cnt += (int)__builtin_popcountll(__ballot(cl & 1)); \
    cnt += (int)__builtin_popcountll(__ballot(cl & 2)) << 1; \
    cnt += (int)__builtin_popcountll(__ballot(cl & 4)) << 2; \
    cnt += (int)__builtin_popcountll(__ballot(cl & 8)) << 3; \
    cnt += (int)__builtin_popcountll(__ballot(cl & 16)) << 4; \
    cnt += (int)__builtin_popcountll(__ballot(cl & 32)) << 5; \
    if (cnt >= KK) { T |= (BITV); E = eb; if (cnt == KK) goto sel_done; } \
    else { gcnt = cnt; E &= ~(TB); } \
}

#define MNU(U) { const unsigned _v = (U) >= T ? (U) : 0xffffffffu; mn = _v < mn ? _v : mn; }

#define EXG(UA, UB, UC, UD, OFF) { \
    const float ea = (UA) >= T ? __expf(ord2f(UA) - mx) : 0.f; \
    const float eb_ = (UB) >= T ? __expf(ord2f(UB) - mx) : 0.f; \
    const float ec = (UC) >= T ? __expf(ord2f(UC) - mx) : 0.f; \
    const float ed = (UD) >= T ? __expf(ord2f(UD) - mx) : 0.f; \
    uint4 wv; \
    wv.x = ((unsigned)f2bf(ea)) << 16; \
    wv.y = ((unsigned)f2bf(eb_)) << 16; \
    wv.z = ((unsigned)f2bf(ec)) << 16; \
    wv.w = ((unsigned)f2bf(ed)) << 16; \
    *(uint4*)(R + (OFF) + lane * 4) = wv; \
    lsum += ea + eb_ + ec + ed; }

__device__ __forceinline__ float row_pass(unsigned* R, const int lane)
{
    // ---- load the lane's 32-element slice: 8x ds_read_b128, all named ----
    const uint4 q0 = *(const uint4*)(R + 0 * 256 + lane * 4);
    const uint4 q1 = *(const uint4*)(R + 1 * 256 + lane * 4);
    const uint4 q2 = *(const uint4*)(R + 2 * 256 + lane * 4);
    const uint4 q3 = *(const uint4*)(R + 3 * 256 + lane * 4);
    const uint4 q4 = *(const uint4*)(R + 4 * 256 + lane * 4);
    const uint4 q5 = *(const uint4*)(R + 5 * 256 + lane * 4);
    const uint4 q6 = *(const uint4*)(R + 6 * 256 + lane * 4);
    const uint4 q7 = *(const uint4*)(R + 7 * 256 + lane * 4);
    const unsigned u0  = q0.x, u1  = q0.y, u2  = q0.z, u3  = q0.w;
    const unsigned u4  = q1.x, u5  = q1.y, u6  = q1.z, u7  = q1.w;
    const unsigned u8  = q2.x, u9  = q2.y, u10 = q2.z, u11 = q2.w;
    const unsigned u12 = q3.x, u13 = q3.y, u14 = q3.z, u15 = q3.w;
    const unsigned u16 = q4.x, u17 = q4.y, u18 = q4.z, u19 = q4.w;
    const unsigned u20 = q5.x, u21 = q5.y, u22 = q5.z, u23 = q5.w;
    const unsigned u24 = q6.x, u25 = q6.y, u26 = q6.z, u27 = q6.w;
    const unsigned u28 = q7.x, u29 = q7.y, u30 = q7.z, u31 = q7.w;

    // ---- row max (tree + wave reduce) ----
    const unsigned a0 = UMX(u0, u1),  a1 = UMX(u2, u3),  a2 = UMX(u4, u5),  a3 = UMX(u6, u7);
    const unsigned a4 = UMX(u8, u9),  a5 = UMX(u10, u11), a6 = UMX(u12, u13), a7 = UMX(u14, u15);
    const unsigned a8 = UMX(u16, u17), a9 = UMX(u18, u19), a10 = UMX(u20, u21), a11 = UMX(u22, u23);
    const unsigned a12 = UMX(u24, u25), a13 = UMX(u26, u27), a14 = UMX(u28, u29), a15 = UMX(u30, u31);
    const unsigned b0 = UMX(a0, a1), b1 = UMX(a2, a3), b2 = UMX(a4, a5), b3 = UMX(a6, a7);
    const unsigned b4 = UMX(a8, a9), b5 = UMX(a10, a11), b6 = UMX(a12, a13), b7 = UMX(a14, a15);
    const unsigned c0 = UMX(b0, b1), c1 = UMX(b2, b3), c2 = UMX(b4, b5), c3 = UMX(b6, b7);
    unsigned umx = UMX(UMX(c0, c1), UMX(c2, c3));
#pragma unroll
    for (int off = 32; off >= 1; off >>= 1) {
        const unsigned o = (unsigned)__shfl_xor((int)umx, off);
        umx = o > umx ? o : umx;
    }
    const float mx = ord2f(umx);

    // ---- 32x32 bit transpose: t{b} bit j = bit b of u{j} ----
    unsigned t0 = u0,  t1 = u1,  t2 = u2,  t3 = u3,  t4 = u4,  t5 = u5,  t6 = u6,  t7 = u7;
    unsigned t8 = u8,  t9 = u9,  t10 = u10, t11 = u11, t12 = u12, t13 = u13, t14 = u14, t15 = u15;
    unsigned t16 = u16, t17 = u17, t18 = u18, t19 = u19, t20 = u20, t21 = u21, t22 = u22, t23 = u23;
    unsigned t24 = u24, t25 = u25, t26 = u26, t27 = u27, t28 = u28, t29 = u29, t30 = u30, t31 = u31;
    // stage J=16
    TRP(t0, t16, 16, 0x0000FFFFu) TRP(t1, t17, 16, 0x0000FFFFu)
    TRP(t2, t18, 16, 0x0000FFFFu) TRP(t3, t19, 16, 0x0000FFFFu)
    TRP(t4, t20, 16, 0x0000FFFFu) TRP(t5, t21, 16, 0x0000FFFFu)
    TRP(t6, t22, 16, 0x0000FFFFu) TRP(t7, t23, 16, 0x0000FFFFu)
    TRP(t8, t24, 16, 0x0000FFFFu) TRP(t9, t25, 16, 0x0000FFFFu)
    TRP(t10, t26, 16, 0x0000FFFFu) TRP(t11, t27, 16, 0x0000FFFFu)
    TRP(t12, t28, 16, 0x0000FFFFu) TRP(t13, t29, 16, 0x0000FFFFu)
    TRP(t14, t30, 16, 0x0000FFFFu) TRP(t15, t31, 16, 0x0000FFFFu)
    // stage J=8
    TRP(t0, t8, 8, 0x00FF00FFu)  TRP(t1, t9, 8, 0x00FF00FFu)
    TRP(t2, t10, 8, 0x00FF00FFu) TRP(t3, t11, 8, 0x00FF00FFu)
    TRP(t4, t12, 8, 0x00FF00FFu) TRP(t5, t13, 8, 0x00FF00FFu)
    TRP(t6, t14, 8, 0x00FF00FFu) TRP(t7, t15, 8, 0x00FF00FFu)
    TRP(t16, t24, 8, 0x00FF00FFu) TRP(t17, t25, 8, 0x00FF00FFu)
    TRP(t18, t26, 8, 0x00FF00FFu) TRP(t19, t27, 8, 0x00FF00FFu)
    TRP(t20, t28, 8, 0x00FF00FFu) TRP(t21, t29, 8, 0x00FF00FFu)
    TRP(t22, t30, 8, 0x00FF00FFu) TRP(t23, t31, 8, 0x00FF00FFu)
    // stage J=4
    TRP(t0, t4, 4, 0x0F0F0F0Fu)  TRP(t1, t5, 4, 0x0F0F0F0Fu)
    TRP(t2, t6, 4, 0x0F0F0F0Fu)  TRP(t3, t7, 4, 0x0F0F0F0Fu)
    TRP(t8, t12, 4, 0x0F0F0F0Fu) TRP(t9, t13, 4, 0x0F0F0F0Fu)
    TRP(t10, t14, 4, 0x0F0F0F0Fu) TRP(t11, t15, 4, 0x0F0F0F0Fu)
    TRP(t16, t20, 4, 0x0F0F0F0Fu) TRP(t17, t21, 4, 0x0F0F0F0Fu)
    TRP(t18, t22, 4, 0x0F0F0F0Fu) TRP(t19, t23, 4, 0x0F0F0F0Fu)
    TRP(t24, t28, 4, 0x0F0F0F0Fu) TRP(t25, t29, 4, 0x0F0F0F0Fu)
    TRP(t26, t30, 4, 0x0F0F0F0Fu) TRP(t27, t31, 4, 0x0F0F0F0Fu)
    // stage J=2
    TRP(t0, t2, 2, 0x33333333u)  TRP(t1, t3, 2, 0x33333333u)
    TRP(t4, t6, 2, 0x33333333u)  TRP(t5, t7, 2, 0x33333333u)
    TRP(t8, t10, 2, 0x33333333u) TRP(t9, t11, 2, 0x33333333u)
    TRP(t12, t14, 2, 0x33333333u) TRP(t13, t15, 2, 0x33333333u)
    TRP(t16, t18, 2, 0x33333333u) TRP(t17, t19, 2, 0x33333333u)
    TRP(t20, t22, 2, 0x33333333u) TRP(t21, t23, 2, 0x33333333u)
    TRP(t24, t26, 2, 0x33333333u) TRP(t25, t27, 2, 0x33333333u)
    TRP(t28, t30, 2, 0x33333333u) TRP(t29, t31, 2, 0x33333333u)
    // stage J=1
    TRP(t0, t1, 1, 0x55555555u)  TRP(t2, t3, 1, 0x55555555u)
    TRP(t4, t5, 1, 0x55555555u)  TRP(t6, t7, 1, 0x55555555u)
    TRP(t8, t9, 1, 0x55555555u)  TRP(t10, t11, 1, 0x55555555u)
    TRP(t12, t13, 1, 0x55555555u) TRP(t14, t15, 1, 0x55555555u)
    TRP(t16, t17, 1, 0x55555555u) TRP(t18, t19, 1, 0x55555555u)
    TRP(t20, t21, 1, 0x55555555u) TRP(t22, t23, 1, 0x55555555u)
    TRP(t24, t25, 1, 0x55555555u) TRP(t26, t27, 1, 0x55555555u)
    TRP(t28, t29, 1, 0x55555555u) TRP(t30, t31, 1, 0x55555555u)

    // ---- rank-count binary search over bit-planes (MSB -> LSB) ----
    unsigned T = 0u, E = 0xffffffffu;
    int gcnt = 0;
    SELSTEP(t31, 1u << 31) SELSTEP(t30, 1u << 30) SELSTEP(t29, 1u << 29) SELSTEP(t28, 1u << 28)
    SELSTEP(t27, 1u << 27) SELSTEP(t26, 1u << 26) SELSTEP(t25, 1u << 25) SELSTEP(t24, 1u << 24)
    SELSTEP(t23, 1u << 23) SELSTEP(t22, 1u << 22) SELSTEP(t21, 1u << 21) SELSTEP(t20, 1u << 20)
    SELSTEP(t19, 1u << 19) SELSTEP(t18, 1u << 18) SELSTEP(t17, 1u << 17) SELSTEP(t16, 1u << 16)
    SELSTEP(t15, 1u << 15) SELSTEP(t14, 1u << 14) SELSTEP(t13, 1u << 13) SELSTEP(t12, 1u << 12)
    SELSTEP(t11, 1u << 11) SELSTEP(t10, 1u << 10) SELSTEP(t9, 1u << 9)   SELSTEP(t8, 1u << 8)
    SELSTEP(t7, 1u << 7)   SELSTEP(t6, 1u << 6)   SELSTEP(t5, 1u << 5)   SELSTEP(t4, 1u << 4)
    SELSTEP(t3, 1u << 3)   SELSTEP(t2, 1u << 2)   SELSTEP(t1, 1u << 1)   SELSTEP(t0, 1u)
sel_done: ;
    // threshold = min{u >= T}  (== T when the loop completed all 32 bits)
    {
        unsigned mn = 0xffffffffu;
        MNU(u0) MNU(u1) MNU(u2) MNU(u3) MNU(u4) MNU(u5) MNU(u6) MNU(u7)
        MNU(u8) MNU(u9) MNU(u10) MNU(u11) MNU(u12) MNU(u13) MNU(u14) MNU(u15)
        MNU(u16) MNU(u17) MNU(u18) MNU(u19) MNU(u20) MNU(u21) MNU(u22) MNU(u23)
        MNU(u24) MNU(u25) MNU(u26) MNU(u27) MNU(u28) MNU(u29) MNU(u30) MNU(u31)
#pragma unroll
        for (int off = 32; off >= 1; off >>= 1) {
            const unsigned o = (unsigned)__shfl_xor((int)mn, off);
            mn = o < mn ? o : mn;
        }
        T = mn;
    }

    // ---- softmax numerators; bf16 P in-place into hi-16 of score words ----
    float lsum = 0.f;
    EXG(u0, u1, u2, u3, 0 * 256)    EXG(u4, u5, u6, u7, 1 * 256)
    EXG(u8, u9, u10, u11, 2 * 256)  EXG(u12, u13, u14, u15, 3 * 256)
    EXG(u16, u17, u18, u19, 4 * 256) EXG(u20, u21, u22, u23, 5 * 256)
    EXG(u24, u25, u26, u27, 6 * 256) EXG(u28, u29, u30, u31, 7 * 256)
#pragma unroll
    for (int off = 32; off >= 1; off >>= 1) lsum += __shfl_xor(lsum, off);
    return 1.f / lsum;
}

// ---------------------------------------------------------------------------
// Fused attention R12 — LDS-resident scores + fully register-resident select.
// ---------------------------------------------------------------------------
__global__ __launch_bounds__(512, 2)
void attn_kernel(const unsigned short* __restrict__ Qh, const unsigned short* __restrict__ Ql,
                 const unsigned short* __restrict__ Kh, const unsigned short* __restrict__ Kl,
                 const unsigned short* __restrict__ Vt,
                 unsigned short* __restrict__ AOh, unsigned short* __restrict__ AOl)
{
    extern __shared__ __align__(16) char smem[];
    unsigned* S = (unsigned*)smem;          // [16][SSTR] ord scores / bf16-P overlay
    float* Opart = (float*)smem;            // overlay [8][16][64] after PV reads done

    const int tid  = threadIdx.x;
    const int lane = tid & 63;
    const int w    = tid >> 6;
    const int q15  = lane & 15;
    const int quad = lane >> 4;

    // XCD swizzle: 4 heads per XCD -> K+V working set ~3 MB, fits 4 MB L2
    const int blk = blockIdx.x;
    const int bh  = (blk & 7) * 4 + ((blk >> 3) & 3);
    const int q0  = (blk >> 5) * 16;

    // ---- Q B-frags direct from global ----
    const size_t qrow = ((size_t)bh * S_LEN + q0 + q15) * HDIM;
    const bf16x8 bqh0 = *(const bf16x8*)(Qh + qrow + quad * 8);
    const bf16x8 bqh1 = *(const bf16x8*)(Qh + qrow + 32 + quad * 8);
    const bf16x8 bql0 = *(const bf16x8*)(Ql + qrow + quad * 8);
    const bf16x8 bql1 = *(const bf16x8*)(Ql + qrow + 32 + quad * 8);

    const size_t kbase = (size_t)bh * S_LEN * HDIM;

    // ---- phase 1: QK^T, all 16 key-tiles per wave, straight to LDS ----
#pragma unroll 4
    for (int t = 0; t < 16; ++t) {
        const int key = w * 256 + t * 16 + q15;     // A-frag m
        const unsigned short* kh = Kh + kbase + (size_t)key * HDIM + quad * 8;
        const unsigned short* kl = Kl + kbase + (size_t)key * HDIM + quad * 8;
        const bf16x8 akh0 = *(const bf16x8*)(kh);
        const bf16x8 akh1 = *(const bf16x8*)(kh + 32);
        const bf16x8 akl0 = *(const bf16x8*)(kl);
        const bf16x8 akl1 = *(const bf16x8*)(kl + 32);
        f32x4 c = {0.f, 0.f, 0.f, 0.f};
        c = __builtin_amdgcn_mfma_f32_16x16x32_bf16(akh0, bqh0, c, 0, 0, 0);
        c = __builtin_amdgcn_mfma_f32_16x16x32_bf16(akh1, bqh1, c, 0, 0, 0);
        c = __builtin_amdgcn_mfma_f32_16x16x32_bf16(akh0, bql0, c, 0, 0, 0);
        c = __builtin_amdgcn_mfma_f32_16x16x32_bf16(akh1, bql1, c, 0, 0, 0);
        c = __builtin_amdgcn_mfma_f32_16x16x32_bf16(akl0, bqh0, c, 0, 0, 0);
        c = __builtin_amdgcn_mfma_f32_16x16x32_bf16(akl1, bqh1, c, 0, 0, 0);
        c = c * 0.125f;
        // C-layout: col=lane&15=q(row of S), row-in-tile=quad*4+reg=key(col)
        uint4 o;
        o.x = f2ord(c[0]); o.y = f2ord(c[1]); o.z = f2ord(c[2]); o.w = f2ord(c[3]);
        *(uint4*)(S + q15 * SSTR + w * 256 + t * 16 + quad * 4) = o;
    }
    __syncthreads();   // full [16][2048] score matrix visible

    // ---- phase 2: per-row select + softmax, in-place bf16 P ----
    const int r0 = 2 * w;
    const float invd0 = row_pass(S + r0 * SSTR, lane);
    const float invd1 = row_pass(S + (r0 + 1) * SSTR, lane);
    __syncthreads();   // all P visible

    // ---- phase 3: dense PV via bf16 MFMA, wave w keys [256w,256w+256) ----
    {
        f32x4 oacc[4];
#pragma unroll
        for (int ht = 0; ht < 4; ++ht) oacc[ht] = (f32x4){0.f, 0.f, 0.f, 0.f};
        const size_t vtb = (size_t)bh * HDIM * S_LEN;
        const unsigned* Srow = S + q15 * SSTR;
#pragma unroll 2
        for (int ks = 0; ks < 8; ++ks) {
            const int key0 = w * 256 + ks * 32 + quad * 8;
            const uint4 a0 = *(const uint4*)(Srow + key0);
            const uint4 a1 = *(const uint4*)(Srow + key0 + 4);
            const bf16x8 ap = pack_hi8(a0, a1);                      // A[m=q][k=key]
#pragma unroll
            for (int ht = 0; ht < 4; ++ht) {
                const int hd = ht * 16 + q15;                        // B[k=key][n=hd]
                const bf16x8 bv = *(const bf16x8*)(Vt + vtb + (size_t)hd * S_LEN + key0);
                oacc[ht] = __builtin_amdgcn_mfma_f32_16x16x32_bf16(ap, bv, oacc[ht], 0, 0, 0);
            }
        }
        __syncthreads();   // all P reads done; score region dead -> Opart live
        // D[m=q][n=hd]: col=lane&15=hd-in-tile, row=quad*4+reg=q
#pragma unroll
        for (int ht = 0; ht < 4; ++ht)
#pragma unroll
            for (int rg = 0; rg < 4; ++rg)
                Opart[w * 1024 + (quad * 4 + rg) * 64 + ht * 16 + q15] = oacc[ht][rg];
    }
    __syncthreads();

    // ---- final: reduce 8 partials, scale, write AO as bf16 hi/lo ----
    {
        const int r1 = r0 + 1;
        float s0 = 0.f, s1 = 0.f;
#pragma unroll
        for (int ww = 0; ww < 8; ++ww) {
            s0 += Opart[ww * 1024 + r0 * 64 + lane];
            s1 += Opart[ww * 1024 + r1 * 64 + lane];
        }
        const int b = bh >> 4, h = bh & 15;
        const float o0 = s0 * invd0;
        const float o1 = s1 * invd1;
        const size_t i0 = ((size_t)(b * S_LEN + q0 + r0)) * DMODEL + h * HDIM + lane;
        const size_t i1 = ((size_t)(b * S_LEN + q0 + r1)) * DMODEL + h * HDIM + lane;
        const unsigned short h0 = f2bf(o0), h1 = f2bf(o1);
        AOh[i0] = h0; AOl[i0] = f2bf(o0 - bf2f(h0));
        AOh[i1] = h1; AOl[i1] = f2bf(o1 - bf2f(h1));
    }
}

// ---------------------------------------------------------------------------
extern "C" void kernel_launch(void* const* d_in, const int* in_sizes, int n_in,
                              void* d_out, int out_size, void* d_ws, size_t ws_size,
                              hipStream_t stream)
{
    const float* X  = (const float*)d_in[0];
    const float* Wq = (const float*)d_in[1];
    const float* bq = (const float*)d_in[2];
    const float* Wk = (const float*)d_in[3];
    const float* bk = (const float*)d_in[4];
    const float* Wv = (const float*)d_in[5];
    const float* bv = (const float*)d_in[6];
    const float* Wo = (const float*)d_in[7];
    const float* bo = (const float*)d_in[8];

    char* p = (char*)d_ws;
    const size_t NEL = (size_t)BHC * S_LEN * HDIM;   // 4,194,304
    unsigned short* Q16h = (unsigned short*)p; p += NEL * 2;
    unsigned short* Q16l = (unsigned short*)p; p += NEL * 2;
    unsigned short* K16h = (unsigned short*)p; p += NEL * 2;
    unsigned short* K16l = (unsigned short*)p; p += NEL * 2;
    unsigned short* Vb16 = (unsigned short*)p; p += NEL * 2;
    unsigned short* Vt16 = (unsigned short*)p; p += NEL * 2;
    unsigned short* Xh   = (unsigned short*)p; p += NEL * 2;
    unsigned short* Xl   = (unsigned short*)p; p += NEL * 2;
    unsigned short* AOh  = (unsigned short*)p; p += NEL * 2;
    unsigned short* AOl  = (unsigned short*)p; p += NEL * 2;
    unsigned short* Wqh  = (unsigned short*)p; p += DMODEL * DMODEL * 2;
    unsigned short* Wql  = (unsigned short*)p; p += DMODEL * DMODEL * 2;
    unsigned short* Wkh  = (unsigned short*)p; p += DMODEL * DMODEL * 2;
    unsigned short* Wkl  = (unsigned short*)p; p += DMODEL * DMODEL * 2;
    unsigned short* Wvh  = (unsigned short*)p; p += DMODEL * DMODEL * 2;
    unsigned short* Wvl  = (unsigned short*)p; p += DMODEL * DMODEL * 2;
    unsigned short* Woh  = (unsigned short*)p; p += DMODEL * DMODEL * 2;
    unsigned short* Wol  = (unsigned short*)p; p += DMODEL * DMODEL * 2;

    const int attn_lds = 16 * SSTR * 4;   // 131,328 B -> 1 block/CU
    hipFuncSetAttribute((const void*)attn_kernel,
                        hipFuncAttributeMaxDynamicSharedMemorySize, attn_lds);

    const int X4 = (int)(NEL / 4);                 // 1,048,576
    const int W4 = DMODEL * DMODEL / 4;            //   262,144

    // ---- input splits ----
    split32<<<(X4 + 255) / 256, 256, 0, stream>>>(X,  Xh,  Xl,  X4);
    split32<<<(W4 + 255) / 256, 256, 0, stream>>>(Wq, Wqh, Wql, W4);
    split32<<<(W4 + 255) / 256, 256, 0, stream>>>(Wk, Wkh, Wkl, W4);
    split32<<<(W4 + 255) / 256, 256, 0, stream>>>(Wv, Wvh, Wvl, W4);
    split32<<<(W4 + 255) / 256, 256, 0, stream>>>(Wo, Woh, Wol, W4);

    // ---- projections (LDS-staged MFMA split-bf16): tiles 128m x 64n ----
    const dim3 ggrid(16, 32, 1);
    gemm_mfma<<<ggrid, 256, 0, stream>>>(Xh, Xl, Wqh, Wql, bq, Q16h, Q16l, 2);
    gemm_mfma<<<ggrid, 256, 0, stream>>>(Xh, Xl, Wkh, Wkl, bk, K16h, K16l, 2);
    gemm_mfma<<<ggrid, 256, 0, stream>>>(Xh, Xl, Wvh, Wvl, bv, Vb16, nullptr, 3);
    transpose_v16<<<dim3(32, 32, 1), 256, 0, stream>>>(Vb16, Vt16);

    // ---- fused attention (R12: register-resident select, zero scratch) ----
    attn_kernel<<<4096, 512, attn_lds, stream>>>(Q16h, Q16l, K16h, K16l, Vt16, AOh, AOl);

    // ---- output projection ----
    gemm_mfma<<<ggrid, 256, 0, stream>>>(AOh, AOl, Woh, Wol, bo, d_out, nullptr, 0);
}

// Round 6
// 787.934 us; speedup vs baseline: 1.1906x; 1.0345x over previous
//
#include <hip/hip_runtime.h>
#include <math.h>

#define S_LEN 2048
#define NH 16
#define HDIM 64
#define BATCH 2
#define BHC 32          // BATCH*NH
#define KK 409          // int(2048 * (1.0 - 0.8)) per reference float math
#define DMODEL 1024

typedef __attribute__((ext_vector_type(8))) short bf16x8;   // 8 bf16 in 4 VGPRs
typedef __attribute__((ext_vector_type(4))) float f32x4;

// LDS-resident score matrix. Row stride in u32 words: 16B-aligned
// (2052 % 4 == 0) and 2052 % 32 == 4 -> no hot bank on any access below.
#define SSTR 2052       // 16 rows * 2052 * 4 B = 131,328 B  -> 1 block/CU
#define T_STR  40       // bf16 LDS tile row stride for gemm: 80 B, 16B-aligned

__device__ __forceinline__ unsigned f2ord(float f) {
    unsigned u = __float_as_uint(f);
    return (u & 0x80000000u) ? ~u : (u | 0x80000000u);
}
__device__ __forceinline__ float ord2f(unsigned v) {
    unsigned u = (v & 0x80000000u) ? (v & 0x7fffffffu) : ~v;
    return __uint_as_float(u);
}
__device__ __forceinline__ unsigned short f2bf(float f) {   // RNE
    unsigned u = __float_as_uint(f);
    u += 0x7fffu + ((u >> 16) & 1u);
    return (unsigned short)(u >> 16);
}
__device__ __forceinline__ float bf2f(unsigned short h) {
    return __uint_as_float(((unsigned)h) << 16);
}

// ---------------------------------------------------------------------------
// fp32 -> bf16 hi/lo split (vectorized float4 / ushort4), n4 = elements/4
// ---------------------------------------------------------------------------
__global__ __launch_bounds__(256)
void split32(const float* __restrict__ in, unsigned short* __restrict__ hi,
             unsigned short* __restrict__ lo, int n4)
{
    const int i = blockIdx.x * 256 + threadIdx.x;
    if (i < n4) {
        const float4 v = ((const float4*)in)[i];
        ushort4 h, l;
        h.x = f2bf(v.x); l.x = f2bf(v.x - bf2f(h.x));
        h.y = f2bf(v.y); l.y = f2bf(v.y - bf2f(h.y));
        h.z = f2bf(v.z); l.z = f2bf(v.z - bf2f(h.z));
        h.w = f2bf(v.w); l.w = f2bf(v.w - bf2f(h.w));
        ((ushort4*)hi)[i] = h;
        ((ushort4*)lo)[i] = l;
    }
}

// ---------------------------------------------------------------------------
// LDS-staged split-bf16 3-pass MFMA GEMM (unchanged — R8 banked structure).
//   C[m][n] = sum_k A[m][k]*B[n][k] + bias[n]
// ---------------------------------------------------------------------------
__global__ __launch_bounds__(256)
void gemm_mfma(const unsigned short* __restrict__ Ah, const unsigned short* __restrict__ Al,
               const unsigned short* __restrict__ Bh, const unsigned short* __restrict__ Bl,
               const float* __restrict__ bias, void* __restrict__ out0,
               void* __restrict__ out1, int mode)
{
    __shared__ __align__(16) unsigned short sAh[128 * T_STR];
    __shared__ __align__(16) unsigned short sAl[128 * T_STR];
    __shared__ __align__(16) unsigned short sBh[64 * T_STR];
    __shared__ __align__(16) unsigned short sBl[64 * T_STR];

    const int tid  = threadIdx.x;
    const int lane = tid & 63;
    const int w    = tid >> 6;
    const int q15  = lane & 15;
    const int quad = lane >> 4;
    const int n0b = blockIdx.x * 64;
    const int m0b = blockIdx.y * 128;
    const int wm = (w >> 1) * 64;
    const int wn = (w & 1) * 32;

    const int ar0 = tid >> 2, aks0 = (tid & 3) * 8;
    const int ar1 = (tid + 256) >> 2, aks1 = aks0;
    const int br = tid >> 2, bks = (tid & 3) * 8;

    const unsigned short* gAh0 = Ah + (size_t)(m0b + ar0) * 1024 + aks0;
    const unsigned short* gAh1 = Ah + (size_t)(m0b + ar1) * 1024 + aks1;
    const unsigned short* gAl0 = Al + (size_t)(m0b + ar0) * 1024 + aks0;
    const unsigned short* gAl1 = Al + (size_t)(m0b + ar1) * 1024 + aks1;
    const unsigned short* gBh = Bh + (size_t)(n0b + br) * 1024 + bks;
    const unsigned short* gBl = Bl + (size_t)(n0b + br) * 1024 + bks;

    f32x4 acc[4][2];
#pragma unroll
    for (int mt = 0; mt < 4; ++mt)
#pragma unroll
        for (int nt = 0; nt < 2; ++nt) acc[mt][nt] = (f32x4){0.f, 0.f, 0.f, 0.f};

#pragma unroll 1
    for (int k0 = 0; k0 < 1024; k0 += 32) {
        const bf16x8 vah0 = *(const bf16x8*)(gAh0 + k0);
        const bf16x8 vah1 = *(const bf16x8*)(gAh1 + k0);
        const bf16x8 val0 = *(const bf16x8*)(gAl0 + k0);
        const bf16x8 val1 = *(const bf16x8*)(gAl1 + k0);
        const bf16x8 vbh  = *(const bf16x8*)(gBh + k0);
        const bf16x8 vbl  = *(const bf16x8*)(gBl + k0);
        __syncthreads();
        *(bf16x8*)(sAh + ar0 * T_STR + aks0) = vah0;
        *(bf16x8*)(sAh + ar1 * T_STR + aks1) = vah1;
        *(bf16x8*)(sAl + ar0 * T_STR + aks0) = val0;
        *(bf16x8*)(sAl + ar1 * T_STR + aks1) = val1;
        *(bf16x8*)(sBh + br * T_STR + bks) = vbh;
        *(bf16x8*)(sBl + br * T_STR + bks) = vbl;
        __syncthreads();

        bf16x8 fbh[2], fbl[2];
#pragma unroll
        for (int nt = 0; nt < 2; ++nt) {
            fbh[nt] = *(const bf16x8*)(sBh + (wn + nt * 16 + q15) * T_STR + quad * 8);
            fbl[nt] = *(const bf16x8*)(sBl + (wn + nt * 16 + q15) * T_STR + quad * 8);
        }
#pragma unroll
        for (int mt = 0; mt < 4; ++mt) {
            const bf16x8 fah = *(const bf16x8*)(sAh + (wm + mt * 16 + q15) * T_STR + quad * 8);
            const bf16x8 fal = *(const bf16x8*)(sAl + (wm + mt * 16 + q15) * T_STR + quad * 8);
#pragma unroll
            for (int nt = 0; nt < 2; ++nt) {
                acc[mt][nt] = __builtin_amdgcn_mfma_f32_16x16x32_bf16(fah, fbh[nt], acc[mt][nt], 0, 0, 0);
                acc[mt][nt] = __builtin_amdgcn_mfma_f32_16x16x32_bf16(fah, fbl[nt], acc[mt][nt], 0, 0, 0);
                acc[mt][nt] = __builtin_amdgcn_mfma_f32_16x16x32_bf16(fal, fbh[nt], acc[mt][nt], 0, 0, 0);
            }
        }
    }

#pragma unroll
    for (int nt = 0; nt < 2; ++nt) {
        const int n = n0b + wn + nt * 16 + q15;
        const float bv = bias[n];
#pragma unroll
        for (int mt = 0; mt < 4; ++mt) {
            const int mb = m0b + wm + mt * 16 + quad * 4;
#pragma unroll
            for (int rg = 0; rg < 4; ++rg) {
                const int m = mb + rg;
                const float o = acc[mt][nt][rg] + bv;
                if (mode == 0) {
                    ((float*)out0)[(size_t)m * 1024 + n] = o;
                } else {
                    const int b = m >> 11, s = m & 2047;
                    const int h = n >> 6, hd = n & 63;
                    const size_t base = ((size_t)((b * NH + h) * S_LEN + s)) * HDIM + hd;
                    if (mode == 3) {
                        ((unsigned short*)out0)[base] = f2bf(o);
                    } else {
                        const unsigned short oh = f2bf(o);
                        ((unsigned short*)out0)[base] = oh;
                        ((unsigned short*)out1)[base] = f2bf(o - bf2f(oh));
                    }
                }
            }
        }
    }
}

// ---------------------------------------------------------------------------
// V bf16 [bh][s][64] -> Vt bf16 [bh][64][2048]  (B-operand layout for PV MFMA)
// ---------------------------------------------------------------------------
__global__ __launch_bounds__(256)
void transpose_v16(const unsigned short* __restrict__ V, unsigned short* __restrict__ Vt)
{
    __shared__ unsigned short t[64][72];
    const int tid = threadIdx.x;
    const int s0 = blockIdx.x * 64;
    const int bh = blockIdx.y;
    const unsigned short* Vb = V + (size_t)bh * S_LEN * HDIM;
#pragma unroll
    for (int i = 0; i < 4; ++i) {
        const int f = tid + i * 256;
        const int s = f >> 4;
        const int hq = (f & 15) * 4;
        const ushort4 v = *(const ushort4*)(Vb + (size_t)(s0 + s) * HDIM + hq);
        t[s][hq + 0] = v.x; t[s][hq + 1] = v.y; t[s][hq + 2] = v.z; t[s][hq + 3] = v.w;
    }
    __syncthreads();
    unsigned short* Vtb = Vt + (size_t)bh * HDIM * S_LEN;
#pragma unroll
    for (int i = 0; i < 4; ++i) {
        const int f = tid + i * 256;
        const int hd = f >> 4;
        const int sq = (f & 15) * 4;
        ushort4 v;
        v.x = t[sq + 0][hd]; v.y = t[sq + 1][hd];
        v.z = t[sq + 2][hd]; v.w = t[sq + 3][hd];
        *(ushort4*)(Vtb + (size_t)hd * S_LEN + s0 + sq) = v;
    }
}

// ---------------------------------------------------------------------------
// pack hi-16 of 8 consecutive score words (= in-place bf16 P) into a bf16x8
// ---------------------------------------------------------------------------
__device__ __forceinline__ bf16x8 pack_hi8(const uint4 a0, const uint4 a1)
{
    union { unsigned u[4]; bf16x8 v; } c;
    c.u[0] = (a0.x >> 16) | (a0.y & 0xffff0000u);
    c.u[1] = (a0.z >> 16) | (a0.w & 0xffff0000u);
    c.u[2] = (a1.x >> 16) | (a1.y & 0xffff0000u);
    c.u[3] = (a1.z >> 16) | (a1.w & 0xffff0000u);
    return c.v;
}

// ---------------------------------------------------------------------------
// R12 phase-2 row pass — ALL NAMED SCALARS, no local arrays (rule #20).
// Select = rank-count binary search on BIT-PLANES (semantics identical to
// the proven R8/R10/R11 rank-count select; verified passing in R12).
// ---------------------------------------------------------------------------
#define TRP(AK, AKJ, J, M) { const unsigned _t = (((AK) >> (J)) ^ (AKJ)) & (M); \
                             (AK) ^= _t << (J); (AKJ) ^= _t; }
#define UMX(A, B) ((A) > (B) ? (A) : (B))

#define SELSTEP(TB, BITV) { \
    const unsigned eb = E & (TB); \
    const int cl = __builtin_popcount(eb); \
    int cnt = gcnt; \
    cnt += (int)__builtin_popcountll(__ballot(cl & 1)); \
    cnt += (int)__builtin_popcountll(__ballot(cl & 2)) << 1; \
    cnt += (int)__builtin_popcountll(__ballot(cl & 4)) << 2; \
    cnt += (int)__builtin_popcountll(__ballot(cl & 8)) << 3; \
    cnt += (int)__builtin_popcountll(__ballot(cl & 16)) << 4; \
    cnt += (int)__builtin_popcountll(__ballot(cl & 32)) << 5; \
    if (cnt >= KK) { T |= (BITV); E = eb; if (cnt == KK) goto sel_done; } \
    else { gcnt = cnt; E &= ~(TB); } \
}

#define MNU(U) { const unsigned _v = (U) >= T ? (U) : 0xffffffffu; mn = _v < mn ? _v : mn; }

#define EXG(UA, UB, UC, UD, OFF) { \
    const float ea = (UA) >= T ? __expf(ord2f(UA) - mx) : 0.f; \
    const float eb_ = (UB) >= T ? __expf(ord2f(UB) - mx) : 0.f; \
    const float ec = (UC) >= T ? __expf(ord2f(UC) - mx) : 0.f; \
    const float ed = (UD) >= T ? __expf(ord2f(UD) - mx) : 0.f; \
    uint4 wv; \
    wv.x = ((unsigned)f2bf(ea)) << 16; \
    wv.y = ((unsigned)f2bf(eb_)) << 16; \
    wv.z = ((unsigned)f2bf(ec)) << 16; \
    wv.w = ((unsigned)f2bf(ed)) << 16; \
    *(uint4*)(R + (OFF) + lane * 4) = wv; \
    lsum += ea + eb_ + ec + ed; }

__device__ __forceinline__ float row_pass(unsigned* R, const int lane)
{
    // ---- load the lane's 32-element slice: 8x ds_read_b128, all named ----
    const uint4 q0 = *(const uint4*)(R + 0 * 256 + lane * 4);
    const uint4 q1 = *(const uint4*)(R + 1 * 256 + lane * 4);
    const uint4 q2 = *(const uint4*)(R + 2 * 256 + lane * 4);
    const uint4 q3 = *(const uint4*)(R + 3 * 256 + lane * 4);
    const uint4 q4 = *(const uint4*)(R + 4 * 256 + lane * 4);
    const uint4 q5 = *(const uint4*)(R + 5 * 256 + lane * 4);
    const uint4 q6 = *(const uint4*)(R + 6 * 256 + lane * 4);
    const uint4 q7 = *(const uint4*)(R + 7 * 256 + lane * 4);
    const unsigned u0  = q0.x, u1  = q0.y, u2  = q0.z, u3  = q0.w;
    const unsigned u4  = q1.x, u5  = q1.y, u6  = q1.z, u7  = q1.w;
    const unsigned u8  = q2.x, u9  = q2.y, u10 = q2.z, u11 = q2.w;
    const unsigned u12 = q3.x, u13 = q3.y, u14 = q3.z, u15 = q3.w;
    const unsigned u16 = q4.x, u17 = q4.y, u18 = q4.z, u19 = q4.w;
    const unsigned u20 = q5.x, u21 = q5.y, u22 = q5.z, u23 = q5.w;
    const unsigned u24 = q6.x, u25 = q6.y, u26 = q6.z, u27 = q6.w;
    const unsigned u28 = q7.x, u29 = q7.y, u30 = q7.z, u31 = q7.w;

    // ---- row max (tree + wave reduce) ----
    const unsigned a0 = UMX(u0, u1),  a1 = UMX(u2, u3),  a2 = UMX(u4, u5),  a3 = UMX(u6, u7);
    const unsigned a4 = UMX(u8, u9),  a5 = UMX(u10, u11), a6 = UMX(u12, u13), a7 = UMX(u14, u15);
    const unsigned a8 = UMX(u16, u17), a9 = UMX(u18, u19), a10 = UMX(u20, u21), a11 = UMX(u22, u23);
    const unsigned a12 = UMX(u24, u25), a13 = UMX(u26, u27), a14 = UMX(u28, u29), a15 = UMX(u30, u31);
    const unsigned b0 = UMX(a0, a1), b1 = UMX(a2, a3), b2 = UMX(a4, a5), b3 = UMX(a6, a7);
    const unsigned b4 = UMX(a8, a9), b5 = UMX(a10, a11), b6 = UMX(a12, a13), b7 = UMX(a14, a15);
    const unsigned c0 = UMX(b0, b1), c1 = UMX(b2, b3), c2 = UMX(b4, b5), c3 = UMX(b6, b7);
    unsigned umx = UMX(UMX(c0, c1), UMX(c2, c3));
#pragma unroll
    for (int off = 32; off >= 1; off >>= 1) {
        const unsigned o = (unsigned)__shfl_xor((int)umx, off);
        umx = o > umx ? o : umx;
    }
    const float mx = ord2f(umx);

    // ---- 32x32 bit transpose: t{b} bit j = bit b of u{j} ----
    unsigned t0 = u0,  t1 = u1,  t2 = u2,  t3 = u3,  t4 = u4,  t5 = u5,  t6 = u6,  t7 = u7;
    unsigned t8 = u8,  t9 = u9,  t10 = u10, t11 = u11, t12 = u12, t13 = u13, t14 = u14, t15 = u15;
    unsigned t16 = u16, t17 = u17, t18 = u18, t19 = u19, t20 = u20, t21 = u21, t22 = u22, t23 = u23;
    unsigned t24 = u24, t25 = u25, t26 = u26, t27 = u27, t28 = u28, t29 = u29, t30 = u30, t31 = u31;
    // stage J=16
    TRP(t0, t16, 16, 0x0000FFFFu) TRP(t1, t17, 16, 0x0000FFFFu)
    TRP(t2, t18, 16, 0x0000FFFFu) TRP(t3, t19, 16, 0x0000FFFFu)
    TRP(t4, t20, 16, 0x0000FFFFu) TRP(t5, t21, 16, 0x0000FFFFu)
    TRP(t6, t22, 16, 0x0000FFFFu) TRP(t7, t23, 16, 0x0000FFFFu)
    TRP(t8, t24, 16, 0x0000FFFFu) TRP(t9, t25, 16, 0x0000FFFFu)
    TRP(t10, t26, 16, 0x0000FFFFu) TRP(t11, t27, 16, 0x0000FFFFu)
    TRP(t12, t28, 16, 0x0000FFFFu) TRP(t13, t29, 16, 0x0000FFFFu)
    TRP(t14, t30, 16, 0x0000FFFFu) TRP(t15, t31, 16, 0x0000FFFFu)
    // stage J=8
    TRP(t0, t8, 8, 0x00FF00FFu)  TRP(t1, t9, 8, 0x00FF00FFu)
    TRP(t2, t10, 8, 0x00FF00FFu) TRP(t3, t11, 8, 0x00FF00FFu)
    TRP(t4, t12, 8, 0x00FF00FFu) TRP(t5, t13, 8, 0x00FF00FFu)
    TRP(t6, t14, 8, 0x00FF00FFu) TRP(t7, t15, 8, 0x00FF00FFu)
    TRP(t16, t24, 8, 0x00FF00FFu) TRP(t17, t25, 8, 0x00FF00FFu)
    TRP(t18, t26, 8, 0x00FF00FFu) TRP(t19, t27, 8, 0x00FF00FFu)
    TRP(t20, t28, 8, 0x00FF00FFu) TRP(t21, t29, 8, 0x00FF00FFu)
    TRP(t22, t30, 8, 0x00FF00FFu) TRP(t23, t31, 8, 0x00FF00FFu)
    // stage J=4
    TRP(t0, t4, 4, 0x0F0F0F0Fu)  TRP(t1, t5, 4, 0x0F0F0F0Fu)
    TRP(t2, t6, 4, 0x0F0F0F0Fu)  TRP(t3, t7, 4, 0x0F0F0F0Fu)
    TRP(t8, t12, 4, 0x0F0F0F0Fu) TRP(t9, t13, 4, 0x0F0F0F0Fu)
    TRP(t10, t14, 4, 0x0F0F0F0Fu) TRP(t11, t15, 4, 0x0F0F0F0Fu)
    TRP(t16, t20, 4, 0x0F0F0F0Fu) TRP(t17, t21, 4, 0x0F0F0F0Fu)
    TRP(t18, t22, 4, 0x0F0F0F0Fu) TRP(t19, t23, 4, 0x0F0F0F0Fu)
    TRP(t24, t28, 4, 0x0F0F0F0Fu) TRP(t25, t29, 4, 0x0F0F0F0Fu)
    TRP(t26, t30, 4, 0x0F0F0F0Fu) TRP(t27, t31, 4, 0x0F0F0F0Fu)
    // stage J=2
    TRP(t0, t2, 2, 0x33333333u)  TRP(t1, t3, 2, 0x33333333u)
    TRP(t4, t6, 2, 0x33333333u)  TRP(t5, t7, 2, 0x33333333u)
    TRP(t8, t10, 2, 0x33333333u) TRP(t9, t11, 2, 0x33333333u)
    TRP(t12, t14, 2, 0x33333333u) TRP(t13, t15, 2, 0x33333333u)
    TRP(t16, t18, 2, 0x33333333u) TRP(t17, t19, 2, 0x33333333u)
    TRP(t20, t22, 2, 0x33333333u) TRP(t21, t23, 2, 0x33333333u)
    TRP(t24, t26, 2, 0x33333333u) TRP(t25, t27, 2, 0x33333333u)
    TRP(t28, t30, 2, 0x33333333u) TRP(t29, t31, 2, 0x33333333u)
    // stage J=1
    TRP(t0, t1, 1, 0x55555555u)  TRP(t2, t3, 1, 0x55555555u)
    TRP(t4, t5, 1, 0x55555555u)  TRP(t6, t7, 1, 0x55555555u)
    TRP(t8, t9, 1, 0x55555555u)  TRP(t10, t11, 1, 0x55555555u)
    TRP(t12, t13, 1, 0x55555555u) TRP(t14, t15, 1, 0x55555555u)
    TRP(t16, t17, 1, 0x55555555u) TRP(t18, t19, 1, 0x55555555u)
    TRP(t20, t21, 1, 0x55555555u) TRP(t22, t23, 1, 0x55555555u)
    TRP(t24, t25, 1, 0x55555555u) TRP(t26, t27, 1, 0x55555555u)
    TRP(t28, t29, 1, 0x55555555u) TRP(t30, t31, 1, 0x55555555u)

    // ---- rank-count binary search over bit-planes (MSB -> LSB) ----
    unsigned T = 0u, E = 0xffffffffu;
    int gcnt = 0;
    SELSTEP(t31, 1u << 31) SELSTEP(t30, 1u << 30) SELSTEP(t29, 1u << 29) SELSTEP(t28, 1u << 28)
    SELSTEP(t27, 1u << 27) SELSTEP(t26, 1u << 26) SELSTEP(t25, 1u << 25) SELSTEP(t24, 1u << 24)
    SELSTEP(t23, 1u << 23) SELSTEP(t22, 1u << 22) SELSTEP(t21, 1u << 21) SELSTEP(t20, 1u << 20)
    SELSTEP(t19, 1u << 19) SELSTEP(t18, 1u << 18) SELSTEP(t17, 1u << 17) SELSTEP(t16, 1u << 16)
    SELSTEP(t15, 1u << 15) SELSTEP(t14, 1u << 14) SELSTEP(t13, 1u << 13) SELSTEP(t12, 1u << 12)
    SELSTEP(t11, 1u << 11) SELSTEP(t10, 1u << 10) SELSTEP(t9, 1u << 9)   SELSTEP(t8, 1u << 8)
    SELSTEP(t7, 1u << 7)   SELSTEP(t6, 1u << 6)   SELSTEP(t5, 1u << 5)   SELSTEP(t4, 1u << 4)
    SELSTEP(t3, 1u << 3)   SELSTEP(t2, 1u << 2)   SELSTEP(t1, 1u << 1)   SELSTEP(t0, 1u)
sel_done: ;
    // threshold = min{u >= T}  (== T when the loop completed all 32 bits)
    {
        unsigned mn = 0xffffffffu;
        MNU(u0) MNU(u1) MNU(u2) MNU(u3) MNU(u4) MNU(u5) MNU(u6) MNU(u7)
        MNU(u8) MNU(u9) MNU(u10) MNU(u11) MNU(u12) MNU(u13) MNU(u14) MNU(u15)
        MNU(u16) MNU(u17) MNU(u18) MNU(u19) MNU(u20) MNU(u21) MNU(u22) MNU(u23)
        MNU(u24) MNU(u25) MNU(u26) MNU(u27) MNU(u28) MNU(u29) MNU(u30) MNU(u31)
#pragma unroll
        for (int off = 32; off >= 1; off >>= 1) {
            const unsigned o = (unsigned)__shfl_xor((int)mn, off);
            mn = o < mn ? o : mn;
        }
        T = mn;
    }

    // ---- softmax numerators; bf16 P in-place into hi-16 of score words ----
    float lsum = 0.f;
    EXG(u0, u1, u2, u3, 0 * 256)    EXG(u4, u5, u6, u7, 1 * 256)
    EXG(u8, u9, u10, u11, 2 * 256)  EXG(u12, u13, u14, u15, 3 * 256)
    EXG(u16, u17, u18, u19, 4 * 256) EXG(u20, u21, u22, u23, 5 * 256)
    EXG(u24, u25, u26, u27, 6 * 256) EXG(u28, u29, u30, u31, 7 * 256)
#pragma unroll
    for (int off = 32; off >= 1; off >>= 1) lsum += __shfl_xor(lsum, off);
    return 1.f / lsum;
}

// ---------------------------------------------------------------------------
// Fused attention R13 — R12 numerics, 16 waves (1024 threads) for TLP.
// (R12 post-mortem: all pipes idle at 23.7% occupancy / 2 waves per SIMD;
//  traffic is gone (20.7 MB fetch), so the floor is exposed latency.  131 KB
//  LDS pins 1 block/CU; the only lever is waves per block: 8 -> 16 gives
//  4 waves/SIMD and halves per-wave serial work in every phase.)
//   phase 1: wave w computes key tiles [128w, 128w+128)   (8 tiles)
//   phase 2: wave w runs row_pass on row w                 (1 row)
//   phase 3: wave w computes PV partial for keys [128w,..) (4 ks)
//   final:   wave w reduces 16 partials for row w
// ---------------------------------------------------------------------------
__global__ __launch_bounds__(1024, 4)
void attn_kernel(const unsigned short* __restrict__ Qh, const unsigned short* __restrict__ Ql,
                 const unsigned short* __restrict__ Kh, const unsigned short* __restrict__ Kl,
                 const unsigned short* __restrict__ Vt,
                 unsigned short* __restrict__ AOh, unsigned short* __restrict__ AOl)
{
    extern __shared__ __align__(16) char smem[];
    unsigned* S = (unsigned*)smem;          // [16][SSTR] ord scores / bf16-P overlay
    float* Opart = (float*)smem;            // overlay [16][16][64] after PV reads done

    const int tid  = threadIdx.x;
    const int lane = tid & 63;
    const int w    = tid >> 6;              // 0..15
    const int q15  = lane & 15;
    const int quad = lane >> 4;

    // XCD swizzle: 4 heads per XCD -> K+V working set ~3 MB, fits 4 MB L2
    const int blk = blockIdx.x;
    const int bh  = (blk & 7) * 4 + ((blk >> 3) & 3);
    const int q0  = (blk >> 5) * 16;

    // ---- Q B-frags direct from global ----
    const size_t qrow = ((size_t)bh * S_LEN + q0 + q15) * HDIM;
    const bf16x8 bqh0 = *(const bf16x8*)(Qh + qrow + quad * 8);
    const bf16x8 bqh1 = *(const bf16x8*)(Qh + qrow + 32 + quad * 8);
    const bf16x8 bql0 = *(const bf16x8*)(Ql + qrow + quad * 8);
    const bf16x8 bql1 = *(const bf16x8*)(Ql + qrow + 32 + quad * 8);

    const size_t kbase = (size_t)bh * S_LEN * HDIM;

    // ---- phase 1: QK^T, 8 key-tiles per wave, straight to LDS ----
#pragma unroll 4
    for (int t = 0; t < 8; ++t) {
        const int key = w * 128 + t * 16 + q15;     // A-frag m
        const unsigned short* kh = Kh + kbase + (size_t)key * HDIM + quad * 8;
        const unsigned short* kl = Kl + kbase + (size_t)key * HDIM + quad * 8;
        const bf16x8 akh0 = *(const bf16x8*)(kh);
        const bf16x8 akh1 = *(const bf16x8*)(kh + 32);
        const bf16x8 akl0 = *(const bf16x8*)(kl);
        const bf16x8 akl1 = *(const bf16x8*)(kl + 32);
        f32x4 c = {0.f, 0.f, 0.f, 0.f};
        c = __builtin_amdgcn_mfma_f32_16x16x32_bf16(akh0, bqh0, c, 0, 0, 0);
        c = __builtin_amdgcn_mfma_f32_16x16x32_bf16(akh1, bqh1, c, 0, 0, 0);
        c = __builtin_amdgcn_mfma_f32_16x16x32_bf16(akh0, bql0, c, 0, 0, 0);
        c = __builtin_amdgcn_mfma_f32_16x16x32_bf16(akh1, bql1, c, 0, 0, 0);
        c = __builtin_amdgcn_mfma_f32_16x16x32_bf16(akl0, bqh0, c, 0, 0, 0);
        c = __builtin_amdgcn_mfma_f32_16x16x32_bf16(akl1, bqh1, c, 0, 0, 0);
        c = c * 0.125f;
        // C-layout: col=lane&15=q(row of S), row-in-tile=quad*4+reg=key(col)
        uint4 o;
        o.x = f2ord(c[0]); o.y = f2ord(c[1]); o.z = f2ord(c[2]); o.w = f2ord(c[3]);
        *(uint4*)(S + q15 * SSTR + w * 128 + t * 16 + quad * 4) = o;
    }
    __syncthreads();   // full [16][2048] score matrix visible

    // ---- phase 2: one row per wave: select + softmax, in-place bf16 P ----
    const float invd = row_pass(S + w * SSTR, lane);
    __syncthreads();   // all P visible

    // ---- phase 3: dense PV via bf16 MFMA, wave w keys [128w,128w+128) ----
    {
        f32x4 oacc[4];
#pragma unroll
        for (int ht = 0; ht < 4; ++ht) oacc[ht] = (f32x4){0.f, 0.f, 0.f, 0.f};
        const size_t vtb = (size_t)bh * HDIM * S_LEN;
        const unsigned* Srow = S + q15 * SSTR;
#pragma unroll 2
        for (int ks = 0; ks < 4; ++ks) {
            const int key0 = w * 128 + ks * 32 + quad * 8;
            const uint4 a0 = *(const uint4*)(Srow + key0);
            const uint4 a1 = *(const uint4*)(Srow + key0 + 4);
            const bf16x8 ap = pack_hi8(a0, a1);                      // A[m=q][k=key]
#pragma unroll
            for (int ht = 0; ht < 4; ++ht) {
                const int hd = ht * 16 + q15;                        // B[k=key][n=hd]
                const bf16x8 bv = *(const bf16x8*)(Vt + vtb + (size_t)hd * S_LEN + key0);
                oacc[ht] = __builtin_amdgcn_mfma_f32_16x16x32_bf16(ap, bv, oacc[ht], 0, 0, 0);
            }
        }
        __syncthreads();   // all P reads done; score region dead -> Opart live
        // D[m=q][n=hd]: col=lane&15=hd-in-tile, row=quad*4+reg=q
#pragma unroll
        for (int ht = 0; ht < 4; ++ht)
#pragma unroll
            for (int rg = 0; rg < 4; ++rg)
                Opart[w * 1024 + (quad * 4 + rg) * 64 + ht * 16 + q15] = oacc[ht][rg];
    }
    __syncthreads();

    // ---- final: wave w reduces 16 partials for row w, writes AO hi/lo ----
    {
        float s = 0.f;
#pragma unroll
        for (int ww = 0; ww < 16; ++ww)
            s += Opart[ww * 1024 + w * 64 + lane];
        const int b = bh >> 4, h = bh & 15;
        const float o = s * invd;
        const size_t i = ((size_t)(b * S_LEN + q0 + w)) * DMODEL + h * HDIM + lane;
        const unsigned short oh = f2bf(o);
        AOh[i] = oh; AOl[i] = f2bf(o - bf2f(oh));
    }
}

// ---------------------------------------------------------------------------
extern "C" void kernel_launch(void* const* d_in, const int* in_sizes, int n_in,
                              void* d_out, int out_size, void* d_ws, size_t ws_size,
                              hipStream_t stream)
{
    const float* X  = (const float*)d_in[0];
    const float* Wq = (const float*)d_in[1];
    const float* bq = (const float*)d_in[2];
    const float* Wk = (const float*)d_in[3];
    const float* bk = (const float*)d_in[4];
    const float* Wv = (const float*)d_in[5];
    const float* bv = (const float*)d_in[6];
    const float* Wo = (const float*)d_in[7];
    const float* bo = (const float*)d_in[8];

    char* p = (char*)d_ws;
    const size_t NEL = (size_t)BHC * S_LEN * HDIM;   // 4,194,304
    unsigned short* Q16h = (unsigned short*)p; p += NEL * 2;
    unsigned short* Q16l = (unsigned short*)p; p += NEL * 2;
    unsigned short* K16h = (unsigned short*)p; p += NEL * 2;
    unsigned short* K16l = (unsigned short*)p; p += NEL * 2;
    unsigned short* Vb16 = (unsigned short*)p; p += NEL * 2;
    unsigned short* Vt16 = (unsigned short*)p; p += NEL * 2;
    unsigned short* Xh   = (unsigned short*)p; p += NEL * 2;
    unsigned short* Xl   = (unsigned short*)p; p += NEL * 2;
    unsigned short* AOh  = (unsigned short*)p; p += NEL * 2;
    unsigned short* AOl  = (unsigned short*)p; p += NEL * 2;
    unsigned short* Wqh  = (unsigned short*)p; p += DMODEL * DMODEL * 2;
    unsigned short* Wql  = (unsigned short*)p; p += DMODEL * DMODEL * 2;
    unsigned short* Wkh  = (unsigned short*)p; p += DMODEL * DMODEL * 2;
    unsigned short* Wkl  = (unsigned short*)p; p += DMODEL * DMODEL * 2;
    unsigned short* Wvh  = (unsigned short*)p; p += DMODEL * DMODEL * 2;
    unsigned short* Wvl  = (unsigned short*)p; p += DMODEL * DMODEL * 2;
    unsigned short* Woh  = (unsigned short*)p; p += DMODEL * DMODEL * 2;
    unsigned short* Wol  = (unsigned short*)p; p += DMODEL * DMODEL * 2;

    const int attn_lds = 16 * SSTR * 4;   // 131,328 B -> 1 block/CU
    hipFuncSetAttribute((const void*)attn_kernel,
                        hipFuncAttributeMaxDynamicSharedMemorySize, attn_lds);

    const int X4 = (int)(NEL / 4);                 // 1,048,576
    const int W4 = DMODEL * DMODEL / 4;            //   262,144

    // ---- input splits ----
    split32<<<(X4 + 255) / 256, 256, 0, stream>>>(X,  Xh,  Xl,  X4);
    split32<<<(W4 + 255) / 256, 256, 0, stream>>>(Wq, Wqh, Wql, W4);
    split32<<<(W4 + 255) / 256, 256, 0, stream>>>(Wk, Wkh, Wkl, W4);
    split32<<<(W4 + 255) / 256, 256, 0, stream>>>(Wv, Wvh, Wvl, W4);
    split32<<<(W4 + 255) / 256, 256, 0, stream>>>(Wo, Woh, Wol, W4);

    // ---- projections (LDS-staged MFMA split-bf16): tiles 128m x 64n ----
    const dim3 ggrid(16, 32, 1);
    gemm_mfma<<<ggrid, 256, 0, stream>>>(Xh, Xl, Wqh, Wql, bq, Q16h, Q16l, 2);
    gemm_mfma<<<ggrid, 256, 0, stream>>>(Xh, Xl, Wkh, Wkl, bk, K16h, K16l, 2);
    gemm_mfma<<<ggrid, 256, 0, stream>>>(Xh, Xl, Wvh, Wvl, bv, Vb16, nullptr, 3);
    transpose_v16<<<dim3(32, 32, 1), 256, 0, stream>>>(Vb16, Vt16);

    // ---- fused attention (R13: 16 waves/block for TLP) ----
    attn_kernel<<<4096, 1024, attn_lds, stream>>>(Q16h, Q16l, K16h, K16l, Vt16, AOh, AOl);

    // ---- output projection ----
    gemm_mfma<<<ggrid, 256, 0, stream>>>(AOh, AOl, Woh, Wol, bo, d_out, nullptr, 0);
}